// Round 14
// baseline (1487.268 us; speedup 1.0000x reference)
//
#include <hip/hip_runtime.h>
#include <math.h>

#define NBATCH 8
#define NATOM  256
#define NP1    257
#define WROW   258
#define TOTALK 9261
#define KCAP   2560
#define KC     16
#define NB     16
#define BD     1024

#define TWO_PI_D 6.283185307179586
#define DIAG_SUB 0.7978845608028654   /* 2/sqrt(2*pi) */

__device__ __constant__ int TI10[10] = {0,0,0,0,1,1,1,2,2,3};
__device__ __constant__ int TJ10[10] = {0,1,2,3,1,2,3,2,3,3};

struct GemmSh {
  int4   kn[KC];
  double kw[KC];
  double cI[KC][64], sI[KC][64];
  double cJ[KC][64], sJ[KC][64];
};

__device__ __forceinline__ void classify2(const void* c0, const void* c1, const void* c2,
                                          const float*& chi, const int*& znum)
{
  const void* cands[3] = {c0, c1, c2};
  int got = 0;
  for (int i = 0; i < 3; i++) {
    unsigned uu = ((const unsigned*)cands[i])[0];
    if (uu == 0u) continue;                                      // batch
    else if (uu < 16u) { znum = (const int*)cands[i]; got |= 1; }// z in {1,6,7,8}
    else               { chi  = (const float*)cands[i]; got |= 2; }
  }
  if (got != 3) { chi = (const float*)c0; znum = (const int*)c1; }
}

// ---------------- K1 (grid 8): trig tables + k-list + aug borders ----------------
__global__ __launch_bounds__(256) void prep(
    const float* __restrict__ pos, const float* __restrict__ cell,
    double2* __restrict__ Tg, int4* __restrict__ klist,
    double* __restrict__ kw, int* __restrict__ kcount,
    const void* __restrict__ c0, const void* __restrict__ c1, const void* __restrict__ c2,
    const float* __restrict__ syschg,
    double* __restrict__ P0g, double* __restrict__ P1g, double* __restrict__ P2g,
    int nplanes)
{
  const int b = blockIdx.x;
  const int tid = threadIdx.x;
  __shared__ double ivs[9];
  __shared__ double prefs;
  __shared__ int cnt;
  if (tid == 0) {
    double c[9];
#pragma unroll
    for (int i = 0; i < 9; i++) c[i] = (double)cell[b*9+i];
    double det = c[0]*(c[4]*c[8]-c[5]*c[7]) - c[1]*(c[3]*c[8]-c[5]*c[6])
               + c[2]*(c[3]*c[7]-c[4]*c[6]);
    double idet = 1.0/det;
    ivs[0]=(c[4]*c[8]-c[5]*c[7])*idet; ivs[1]=(c[2]*c[7]-c[1]*c[8])*idet; ivs[2]=(c[1]*c[5]-c[2]*c[4])*idet;
    ivs[3]=(c[5]*c[6]-c[3]*c[8])*idet; ivs[4]=(c[0]*c[8]-c[2]*c[6])*idet; ivs[5]=(c[2]*c[3]-c[0]*c[5])*idet;
    ivs[6]=(c[3]*c[7]-c[4]*c[6])*idet; ivs[7]=(c[1]*c[6]-c[0]*c[7])*idet; ivs[8]=(c[0]*c[4]-c[1]*c[3])*idet;
    prefs = 2.0*TWO_PI_D/fabs(det);
    cnt = 0;
  }
  __syncthreads();
  {
    const int a = tid;
    double x = (double)pos[((size_t)b*NATOM+a)*3+0];
    double y = (double)pos[((size_t)b*NATOM+a)*3+1];
    double z = (double)pos[((size_t)b*NATOM+a)*3+2];
    double u[3];
    u[0] = TWO_PI_D*(ivs[0]*x + ivs[3]*y + ivs[6]*z);
    u[1] = TWO_PI_D*(ivs[1]*x + ivs[4]*y + ivs[7]*z);
    u[2] = TWO_PI_D*(ivs[2]*x + ivs[5]*y + ivs[8]*z);
#pragma unroll
    for (int d = 0; d < 3; d++) {
      double2* T = Tg + (size_t)((b*3 + d)*21)*256;
      double c1 = cos(u[d]);
      double s1 = sin(u[d]);
      T[10*256 + a] = make_double2(1.0, 0.0);
      T[11*256 + a] = make_double2(c1,  s1);
      T[ 9*256 + a] = make_double2(c1, -s1);
      double cp = c1, sp = s1;
      for (int n = 2; n <= 10; n++) {
        double cn = cp*c1 - sp*s1;
        double sn = sp*c1 + cp*s1;
        cp = cn; sp = sn;
        T[(10+n)*256 + a] = make_double2(cp,  sp);
        T[(10-n)*256 + a] = make_double2(cp, -sp);
      }
    }
  }
  const double ksqmax = (TWO_PI_D/1.5)*(TWO_PI_D/1.5);
  for (int m = tid; m < TOTALK; m += 256) {
    int n1 = m/441 - 10;
    int n2 = (m/21)%21 - 10;
    int n3 = m%21 - 10;
    bool half = (n1 > 0) || (n1 == 0 && (n2 > 0 || (n2 == 0 && n3 > 0)));
    if (!half) continue;
    double d1 = n1, d2 = n2, d3 = n3;
    double kx = TWO_PI_D*(ivs[0]*d1 + ivs[1]*d2 + ivs[2]*d3);
    double ky = TWO_PI_D*(ivs[3]*d1 + ivs[4]*d2 + ivs[5]*d3);
    double kz = TWO_PI_D*(ivs[6]*d1 + ivs[7]*d2 + ivs[8]*d3);
    double k2 = kx*kx + ky*ky + kz*kz;
    if (k2 > 1e-10 && k2 < ksqmax) {
      double w = 2.0 * prefs * exp(-0.5*k2) / k2;
      int slot = atomicAdd(&cnt, 1);
      klist[b*KCAP + slot] = make_int4(n1, n2, n3, 0);
      kw[b*KCAP + slot] = w;
    }
  }
  // aug borders (plane0 real values, planes 1,2 zeros)
  {
    const float* chi = nullptr; const int* znum = nullptr;
    classify2(c0, c1, c2, chi, znum);
    double* P0b = P0g + (size_t)b*NP1*WROW;
    double* P1b = P1g + (size_t)b*NP1*WROW;
    double* P2b = P2g + (size_t)b*NP1*WROW;
    for (int i = tid; i < NATOM; i += 256) {
      P0b[(size_t)NATOM*WROW + i] = 1.0;
      P0b[(size_t)i*WROW + NATOM] = 1.0;
      P0b[(size_t)i*WROW + 257]   = -(double)chi[b*NATOM + i];
      if (nplanes > 1) {
        P1b[(size_t)NATOM*WROW + i] = 0.0;
        P1b[(size_t)i*WROW + NATOM] = 0.0;
        P1b[(size_t)i*WROW + 257]   = 0.0;
      }
      if (nplanes > 2) {
        P2b[(size_t)NATOM*WROW + i] = 0.0;
        P2b[(size_t)i*WROW + NATOM] = 0.0;
        P2b[(size_t)i*WROW + 257]   = 0.0;
      }
    }
    if (tid == 0) {
      P0b[(size_t)NATOM*WROW + NATOM] = 0.0;
      P0b[(size_t)NATOM*WROW + 257]   = (double)syschg[b]*sqrt(90.0474);
      if (nplanes > 1) {
        P1b[(size_t)NATOM*WROW + NATOM] = 0.0;
        P1b[(size_t)NATOM*WROW + 257]   = 0.0;
      }
      if (nplanes > 2) {
        P2b[(size_t)NATOM*WROW + NATOM] = 0.0;
        P2b[(size_t)NATOM*WROW + 257]   = 0.0;
      }
    }
  }
  __syncthreads();
  if (tid == 0) kcount[b] = cnt;
}

// ---------------- fp64 tile GEMM into aug-geometry plane ----------------
__device__ void gemm_tile(int b, int ti, int tj, int tid,
                          const double2* __restrict__ Tg,
                          const int4* __restrict__ klist,
                          const double* __restrict__ kw, int ks, int ke,
                          double* __restrict__ Ab, bool mirror, GemmSh& S)
{
  const int tx = tid & 15, ty = tid >> 4;
  const int ro = ty << 2, co = tx << 2;
  double acc[16];
#pragma unroll
  for (int i = 0; i < 16; i++) acc[i] = 0.0;

  for (int k0 = ks; k0 < ke; k0 += KC) {
    if (tid < KC) {
      int kk = k0 + tid;
      if (kk < ke) { S.kn[tid] = klist[b*KCAP + kk]; S.kw[tid] = kw[b*KCAP + kk]; }
      else         { S.kn[tid] = make_int4(0,0,0,0); S.kw[tid] = 0.0; }
    }
    __syncthreads();
#pragma unroll
    for (int p = 0; p < 8; p++) {
      int idx = p*256 + tid;
      int a    = idx & 63;
      int kk   = (idx >> 6) & (KC-1);
      int side = idx >> 10;
      int atom = ((side == 0) ? ti : tj) + a;
      int4 nn = S.kn[kk];
      double2 t1 = Tg[(size_t)((b*3+0)*21 + (nn.x+10))*256 + atom];
      double2 t2 = Tg[(size_t)((b*3+1)*21 + (nn.y+10))*256 + atom];
      double2 t3 = Tg[(size_t)((b*3+2)*21 + (nn.z+10))*256 + atom];
      double ex = t1.x*t2.x - t1.y*t2.y;
      double ey = t1.x*t2.y + t1.y*t2.x;
      double cx = ex*t3.x - ey*t3.y;
      double cy = ex*t3.y + ey*t3.x;
      if (side == 0) { double w = S.kw[kk]; S.cI[kk][a] = w*cx; S.sI[kk][a] = w*cy; }
      else           { S.cJ[kk][a] = cx; S.sJ[kk][a] = cy; }
    }
    __syncthreads();
#pragma unroll
    for (int kk = 0; kk < KC; kk++) {
      double ci[4], si[4], cj[4], sj[4];
#pragma unroll
      for (int r = 0; r < 2; r++) {
        double2 v0 = *(const double2*)&S.cI[kk][ro + 2*r];
        ci[2*r] = v0.x; ci[2*r+1] = v0.y;
        double2 v1 = *(const double2*)&S.sI[kk][ro + 2*r];
        si[2*r] = v1.x; si[2*r+1] = v1.y;
        double2 v2 = *(const double2*)&S.cJ[kk][co + 2*r];
        cj[2*r] = v2.x; cj[2*r+1] = v2.y;
        double2 v3 = *(const double2*)&S.sJ[kk][co + 2*r];
        sj[2*r] = v3.x; sj[2*r+1] = v3.y;
      }
#pragma unroll
      for (int r = 0; r < 4; r++)
#pragma unroll
        for (int c = 0; c < 4; c++)
          acc[r*4+c] += ci[r]*cj[c] + si[r]*sj[c];
    }
    __syncthreads();
  }
#pragma unroll
  for (int r = 0; r < 4; r++) {
#pragma unroll
    for (int c = 0; c < 4; c++) {
      int gr = ti + ro + r, gc = tj + co + c;
      double v = acc[r*4+c];
      Ab[(size_t)gr*WROW + gc] = v;
      if (mirror && ti != tj) Ab[(size_t)gc*WROW + gr] = v;
    }
  }
  __syncthreads();
}

__device__ __forceinline__ double* plane_sel(double* P0, double* P1, double* P2, int s) {
  return (s == 0) ? P0 : ((s == 1) ? P1 : P2);
}

// ---------------- K2 (grid 80*nplanes): tiles x batches x k-splits ----------------
__global__ __launch_bounds__(256) void build_A_gemm(
    const double2* __restrict__ Tg, const int4* __restrict__ klist,
    const double* __restrict__ kw, const int* __restrict__ kcount,
    double* __restrict__ P0g, double* __restrict__ P1g, double* __restrict__ P2g,
    int nplanes)
{
  __shared__ GemmSh S;
  const int u = blockIdx.x;
  const int s = u / 80;
  const int r = u - s*80;
  const int b = r / 10;
  const int t = r - b*10;
  const int cnt = kcount[b];
  const int ks = (int)((long long)cnt * s / nplanes);
  const int ke = (int)((long long)cnt * (s+1) / nplanes);
  double* Ab = plane_sel(P0g, P1g, P2g, s) + (size_t)b*NP1*WROW;
  gemm_tile(b, TI10[t]*64, TJ10[t]*64, threadIdx.x, Tg, klist, kw, ks, ke, Ab, true, S);
}

// ---------------- K3 (grid 8): exact-poison tile check + rebuild ----------------
__global__ __launch_bounds__(256) void finish_A(
    const double2* __restrict__ Tg, const int4* __restrict__ klist,
    const double* __restrict__ kw, const int* __restrict__ kcount,
    double* __restrict__ P0g, double* __restrict__ P1g, double* __restrict__ P2g,
    int nplanes)
{
  __shared__ GemmSh S;
  const int b = blockIdx.x;
  const int tid = threadIdx.x;
  const int cnt = kcount[b];
  for (int s = 0; s < nplanes; s++) {
    const int ks = (int)((long long)cnt * s / nplanes);
    const int ke = (int)((long long)cnt * (s+1) / nplanes);
    double* Ab = plane_sel(P0g, P1g, P2g, s) + (size_t)b*NP1*WROW;
    for (int t = 0; t < 16; t++) {
      const int ti = (t >> 2)*64, tj = (t & 3)*64;
      int bad = 0;
#pragma unroll
      for (int k = 0; k < 8; k++) {
        int p = (tid << 4) + k;
        int r = p >> 6, c = p & 63;
        double v = Ab[(size_t)(ti+r)*WROW + tj + c];
        if (__double_as_longlong(v) == (long long)0xAAAAAAAAAAAAAAAAULL) bad = 1;
      }
      if (__syncthreads_or(bad))
        gemm_tile(b, ti, tj, tid, Tg, klist, kw, ks, ke, Ab, false, S);
      __syncthreads();
    }
  }
}

// ---------------- K4 (grid 8, block 1024): LU solve, wave-0 panel factor ----------------
__global__ __launch_bounds__(BD) void solve_all(
    double* __restrict__ P0g, const double* __restrict__ P1g, const double* __restrict__ P2g,
    int nplanes,
    const void* __restrict__ c0, const void* __restrict__ c1, const void* __restrict__ c2,
    const float* __restrict__ Jraw, const float* __restrict__ syschg,
    float* __restrict__ out)
{
  const int b = blockIdx.x;
  const int tid = threadIdx.x;
  const int lane = tid & 63;
  double* Pb = P0g + (size_t)b*NP1*WROW;
  const double* Qb = P1g + (size_t)b*NP1*WROW;
  const double* Rb = P2g + (size_t)b*NP1*WROW;
  const bool two   = (nplanes > 1);
  const bool three = (nplanes > 2);

  __shared__ double pan[NP1][18];
  __shared__ double Ub[NB][256];
  __shared__ double xs[NP1];
  __shared__ double red[BD];
  __shared__ int perm[NP1];

  const float* chi = nullptr; const int* znum = nullptr;
  classify2(c0, c1, c2, chi, znum);
  const double rhsN = (double)syschg[b] * sqrt(90.0474);
  const float J0 = Jraw[0], J1 = Jraw[1], J2 = Jraw[2], J3 = Jraw[3];

  for (int i = tid; i < NP1; i += BD) perm[i] = i;
  __syncthreads();

  for (int p0 = 0; p0 < NP1; p0 += NB) {
    const int pw  = (NB < NP1 - p0) ? NB : (NP1 - p0);
    const int nr  = NP1 - p0;
    const int nrt = nr - pw;
    const int tc0 = p0 + pw;
    const int tc  = WROW - tc0;
    const bool first = (p0 == 0);
    // ---- panel load (first panel: fused plane-sum + diag; perm identity then) ----
    for (int idx = tid; idx < nr*pw; idx += BD) {
      int r = (pw == NB) ? (idx >> 4) : (idx / pw);
      int c = (pw == NB) ? (idx & 15) : (idx - r*pw);
      double v;
      if (first) {
        size_t a = (size_t)r*WROW + c;
        v = Pb[a];
        if (two)   v += Qb[a];
        if (three) v += Rb[a];
        if (r == c) {
          int z = znum[b*NATOM + r];
          float Jr = (z == 1) ? J0 : (z == 6) ? J1 : (z == 7) ? J2 : J3;
          v += (double)Jr*(double)Jr - DIAG_SUB;
        }
      } else {
        v = Pb[(size_t)perm[p0+r]*WROW + p0 + c];
      }
      pan[r][c] = v;
    }
    __syncthreads();
    // ---- factor panel ENTIRELY in wave 0 (eager full-width; no block barriers) ----
    if (tid < 64) {
      volatile double (*vp)[18] = (volatile double (*)[18])pan;
      for (int c = 0; c < pw; c++) {
        double best = -1.0; int bi = c;
        for (int r = c + lane; r < nr; r += 64) {
          double av = fabs(vp[r][c]);
          if (av > best) { best = av; bi = r; }
        }
#pragma unroll
        for (int off = 32; off > 0; off >>= 1) {
          double ov = __shfl_down(best, off);
          int    oi = __shfl_down(bi, off);
          if (ov > best) { best = ov; bi = oi; }
        }
        int pr = __shfl(bi, 0);
        if (pr != c) {
          if (lane < pw) {
            double t = vp[c][lane]; vp[c][lane] = vp[pr][lane]; vp[pr][lane] = t;
          }
          if (lane == 0) {
            int t = perm[p0+c]; perm[p0+c] = perm[p0+pr]; perm[p0+pr] = t;
          }
        }
        const double dinv = 1.0 / vp[c][c];
        for (int r = c + 1 + lane; r < nr; r += 64) {
          double f = vp[r][c] * dinv;
          vp[r][c] = f;
          for (int cc = c + 1; cc < pw; cc++) vp[r][cc] -= f * vp[c][cc];
        }
      }
    }
    __syncthreads();
    // ---- write back panel (L and U parts) via perm ----
    for (int idx = tid; idx < nr*pw; idx += BD) {
      int r = (pw == NB) ? (idx >> 4) : (idx / pw);
      int c = (pw == NB) ? (idx & 15) : (idx - r*pw);
      Pb[(size_t)perm[p0+r]*WROW + p0 + c] = pan[r][c];
    }
    __syncthreads();
    // ---- TRSM (thread-per-column) + trailing rank-16 update (double2) ----
    if (pw == NB) {
      if (tid < tc) {
        const int j = tc0 + tid;
        double v[NB];
#pragma unroll
        for (int c = 0; c < NB; c++) {
          const int pr = perm[p0+c];
          size_t a = (size_t)pr*WROW + j;
          double t = Pb[a];
          if (first) {
            if (two)   t += Qb[a];
            if (three) t += Rb[a];
            if (pr == j && pr < NATOM) {          // diag keyed on PHYSICAL row
              int z = znum[b*NATOM + pr];
              float Jr = (z == 1) ? J0 : (z == 6) ? J1 : (z == 7) ? J2 : J3;
              t += (double)Jr*(double)Jr - DIAG_SUB;
            }
          }
          v[c] = t;
        }
#pragma unroll
        for (int c = 0; c < NB; c++)
#pragma unroll
          for (int r = c+1; r < NB; r++) v[r] -= pan[r][c]*v[c];
#pragma unroll
        for (int c = 0; c < NB; c++) {
          Pb[(size_t)perm[p0+c]*WROW + j] = v[c];
          Ub[c][tid] = v[c];
        }
      }
      __syncthreads();
      {
        // col-pair x 8 row-groups: tc is always even, tc0 even -> 16B aligned
        const int jp = tid & 127;          // pair index
        const int rgroup = tid >> 7;       // 0..7
        if (2*jp < tc) {
          const int j0 = 2*jp, j1 = 2*jp + 1;
          double va[NB], vb[NB];
#pragma unroll
          for (int c = 0; c < NB; c++) { va[c] = Ub[c][j0]; vb[c] = Ub[c][j1]; }
          for (int rr = rgroup; rr < nrt; rr += 8) {
            const int prr = perm[tc0 + rr];
            const size_t addr = (size_t)prr*WROW + tc0 + j0;
            double2 a = *(double2*)&Pb[addr];
            if (first) {
              if (two)   { double2 q2 = *(const double2*)&Qb[addr]; a.x += q2.x; a.y += q2.y; }
              if (three) { double2 r2 = *(const double2*)&Rb[addr]; a.x += r2.x; a.y += r2.y; }
              if (prr < NATOM) {
                if (prr == tc0 + j0 || prr == tc0 + j1) {
                  int z = znum[b*NATOM + prr];
                  float Jr = (z == 1) ? J0 : (z == 6) ? J1 : (z == 7) ? J2 : J3;
                  double dv = (double)Jr*(double)Jr - DIAG_SUB;
                  if (prr == tc0 + j0) a.x += dv; else a.y += dv;
                }
              }
            }
#pragma unroll
            for (int m = 0; m < 8; m++) {
              double2 p2 = *(const double2*)&pan[NB+rr][2*m];
              a.x -= p2.x * va[2*m] + p2.y * va[2*m+1];
              a.y -= p2.x * vb[2*m] + p2.y * vb[2*m+1];
            }
            *(double2*)&Pb[addr] = a;
          }
        }
      }
    } else {
      // last panel (pw < NB, no trailing rows; never the first panel)
      if (tid < tc) {
        const int j = tc0 + tid;
        double v[NB];
        for (int c = 0; c < pw; c++) v[c] = Pb[(size_t)perm[p0+c]*WROW + j];
        for (int c = 0; c < pw; c++)
          for (int r = c+1; r < pw; r++) v[r] -= pan[r][c]*v[c];
        for (int c = 0; c < pw; c++) Pb[(size_t)perm[p0+c]*WROW + j] = v[c];
      }
    }
    __syncthreads();
  }

  // ---- blocked backsolve (perm-indirected) ----
  for (int r = tid; r < NP1; r += BD) xs[r] = Pb[(size_t)perm[r]*WROW + 257];
  __syncthreads();
  for (int pb0 = 256; pb0 >= 0; pb0 -= NB) {
    const int w = (pb0 == 256) ? 1 : NB;
    if (tid < w*w) {
      int i = (w == NB) ? (tid >> 4) : 0;
      int c = (w == NB) ? (tid & 15) : 0;
      pan[i][c] = Pb[(size_t)perm[pb0+i]*WROW + pb0 + c];
    }
    __syncthreads();
    if (tid == 0) {
      for (int i = w-1; i >= 0; i--) {
        double s = xs[pb0+i];
        for (int c = i+1; c < w; c++) s -= pan[i][c]*xs[pb0+c];
        xs[pb0+i] = s / pan[i][i];
      }
    }
    __syncthreads();
    if (tid < pb0) {
      const double* rowp = &Pb[(size_t)perm[tid]*WROW + pb0];
      double s = 0.0;
      for (int c = 0; c < w; c++) s += rowp[c]*xs[pb0+c];
      xs[tid] -= s;
    }
    __syncthreads();
  }

  // ---- outputs: q + residual-identity energy ----
  for (int i = tid; i < NATOM; i += BD) out[b*NATOM + i] = (float)xs[i];
  const double lam = xs[NATOM];
  double contrib = 0.0;
  if (tid < NATOM) {
    double q  = xs[tid];
    double ch = (double)chi[b*NATOM + tid];
    int z = znum[b*NATOM + tid];
    float Jr = (z == 1) ? J0 : (z == 6) ? J1 : (z == 7) ? J2 : J3;
    contrib = q*ch + (double)Jr*(double)Jr*q*q;
  }
  __syncthreads();
  red[tid] = contrib;
  __syncthreads();
  for (int st = BD/2; st > 0; st >>= 1) {
    if (tid < st) red[tid] += red[tid + st];
    __syncthreads();
  }
  if (tid == 0)
    out[NBATCH*NATOM + b] = (float)(-0.5*(red[0] + lam*rhsN));
}

// ---------------- host launch ----------------
extern "C" void kernel_launch(void* const* d_in, const int* in_sizes, int n_in,
                              void* d_out, int out_size, void* d_ws, size_t ws_size,
                              hipStream_t stream)
{
  int iPos=-1, iCell=-1, iJ=-1, iQ=-1, cand[3]={-1,-1,-1}, nc=0;
  for (int i = 0; i < n_in; i++) {
    int s = in_sizes[i];
    if      (s == 6144) iPos  = i;
    else if (s == 72)   iCell = i;
    else if (s == 4)    iJ    = i;
    else if (s == 8)    iQ    = i;
    else if (s == 2048 && nc < 3) cand[nc++] = i;
  }
  if (!(iPos>=0 && iCell>=0 && iJ>=0 && iQ>=0 && nc>=2)) {
    iPos=iCell=iJ=iQ=-1; nc=0; cand[0]=cand[1]=cand[2]=-1;
    for (int i = 0; i < n_in; i++) {
      int s = in_sizes[i];
      if      (s == 24576) iPos  = i;
      else if (s == 288)   iCell = i;
      else if (s == 16)    iJ    = i;
      else if (s == 32)    iQ    = i;
      else if (s == 8192 && nc < 3) cand[nc++] = i;
    }
  }
  if (!(iPos>=0 && iCell>=0 && iJ>=0 && iQ>=0 && nc>=2)) {
    iPos=0; iCell=1; iJ=3; iQ=4; cand[0]=2; cand[1]=5; cand[2]=6; nc=3;
  }
  if (nc == 2) cand[2] = cand[1];

  const float* pos  = (const float*)d_in[iPos];
  const float* cell = (const float*)d_in[iCell];
  const float* Jraw = (const float*)d_in[iJ];
  const float* sysq = (const float*)d_in[iQ];
  const void*  c0   = d_in[cand[0]];
  const void*  c1   = d_in[cand[1]];
  const void*  c2   = d_in[cand[2]];
  float* out = (float*)d_out;

  // ws: [plane0][plane1][plane2][Tg][klist][kw][kcount]
  const size_t planeB = (size_t)NBATCH*NP1*WROW*sizeof(double);  // 4,243,584
  const size_t tgB = 2064384, klB = 327680, kwB = 163840;
  const size_t trigAll = tgB + klB + kwB + 64;
  int nplanes = (ws_size >= 3*planeB + trigAll) ? 3 :
                ((ws_size >= 2*planeB + trigAll) ? 2 : 1);

  char* ws = (char*)d_ws;
  double*  P0g = (double*)ws;
  double*  P1g = (nplanes > 1) ? (double*)(ws + planeB)   : P0g;
  double*  P2g = (nplanes > 2) ? (double*)(ws + 2*planeB) : P1g;
  char* trigBase = ws + (size_t)nplanes*planeB;
  double2* Tg     = (double2*)trigBase;
  int4*    klist  = (int4*)  (trigBase + tgB);
  double*  kwa    = (double*)(trigBase + tgB + klB);
  int*     kcount = (int*)   (trigBase + tgB + klB + kwB);

  hipLaunchKernelGGL(prep,         dim3(NBATCH),      dim3(256), 0, stream,
                     pos, cell, Tg, klist, kwa, kcount, c0, c1, c2, sysq,
                     P0g, P1g, P2g, nplanes);
  hipLaunchKernelGGL(build_A_gemm, dim3(80*nplanes),  dim3(256), 0, stream,
                     Tg, klist, kwa, kcount, P0g, P1g, P2g, nplanes);
  hipLaunchKernelGGL(finish_A,     dim3(NBATCH),      dim3(256), 0, stream,
                     Tg, klist, kwa, kcount, P0g, P1g, P2g, nplanes);
  hipLaunchKernelGGL(solve_all,    dim3(NBATCH),      dim3(BD),  0, stream,
                     P0g, P1g, P2g, nplanes, c0, c1, c2, Jraw, sysq, out);
}

// Round 15
// 782.294 us; speedup vs baseline: 1.9012x; 1.9012x over previous
//
#include <hip/hip_runtime.h>
#include <math.h>

#define NBATCH 8
#define NATOM  256
#define NP1    257
#define WROW   258
#define TOTALK 9261
#define KCAP   2560
#define KC     16
#define NB     16
#define BD     1024

#define TWO_PI_D 6.283185307179586
#define DIAG_SUB 0.7978845608028654   /* 2/sqrt(2*pi) */

__device__ __constant__ int TI10[10] = {0,0,0,0,1,1,1,2,2,3};
__device__ __constant__ int TJ10[10] = {0,1,2,3,1,2,3,2,3,3};

struct GemmSh {
  int4   kn[KC];
  double kw[KC];
  double cI[KC][64], sI[KC][64];
  double cJ[KC][64], sJ[KC][64];
};

__device__ __forceinline__ void classify2(const void* c0, const void* c1, const void* c2,
                                          const float*& chi, const int*& znum)
{
  const void* cands[3] = {c0, c1, c2};
  int got = 0;
  for (int i = 0; i < 3; i++) {
    unsigned uu = ((const unsigned*)cands[i])[0];
    if (uu == 0u) continue;                                      // batch
    else if (uu < 16u) { znum = (const int*)cands[i]; got |= 1; }// z in {1,6,7,8}
    else               { chi  = (const float*)cands[i]; got |= 2; }
  }
  if (got != 3) { chi = (const float*)c0; znum = (const int*)c1; }
}

// ---------------- K1 (grid 8): trig tables + k-list + aug borders ----------------
__global__ __launch_bounds__(256) void prep(
    const float* __restrict__ pos, const float* __restrict__ cell,
    double2* __restrict__ Tg, int4* __restrict__ klist,
    double* __restrict__ kw, int* __restrict__ kcount,
    const void* __restrict__ c0, const void* __restrict__ c1, const void* __restrict__ c2,
    const float* __restrict__ syschg,
    double* __restrict__ P0g, double* __restrict__ P1g, double* __restrict__ P2g,
    int nplanes)
{
  const int b = blockIdx.x;
  const int tid = threadIdx.x;
  __shared__ double ivs[9];
  __shared__ double prefs;
  __shared__ int cnt;
  if (tid == 0) {
    double c[9];
#pragma unroll
    for (int i = 0; i < 9; i++) c[i] = (double)cell[b*9+i];
    double det = c[0]*(c[4]*c[8]-c[5]*c[7]) - c[1]*(c[3]*c[8]-c[5]*c[6])
               + c[2]*(c[3]*c[7]-c[4]*c[6]);
    double idet = 1.0/det;
    ivs[0]=(c[4]*c[8]-c[5]*c[7])*idet; ivs[1]=(c[2]*c[7]-c[1]*c[8])*idet; ivs[2]=(c[1]*c[5]-c[2]*c[4])*idet;
    ivs[3]=(c[5]*c[6]-c[3]*c[8])*idet; ivs[4]=(c[0]*c[8]-c[2]*c[6])*idet; ivs[5]=(c[2]*c[3]-c[0]*c[5])*idet;
    ivs[6]=(c[3]*c[7]-c[4]*c[6])*idet; ivs[7]=(c[1]*c[6]-c[0]*c[7])*idet; ivs[8]=(c[0]*c[4]-c[1]*c[3])*idet;
    prefs = 2.0*TWO_PI_D/fabs(det);
    cnt = 0;
  }
  __syncthreads();
  {
    const int a = tid;
    double x = (double)pos[((size_t)b*NATOM+a)*3+0];
    double y = (double)pos[((size_t)b*NATOM+a)*3+1];
    double z = (double)pos[((size_t)b*NATOM+a)*3+2];
    double u[3];
    u[0] = TWO_PI_D*(ivs[0]*x + ivs[3]*y + ivs[6]*z);
    u[1] = TWO_PI_D*(ivs[1]*x + ivs[4]*y + ivs[7]*z);
    u[2] = TWO_PI_D*(ivs[2]*x + ivs[5]*y + ivs[8]*z);
#pragma unroll
    for (int d = 0; d < 3; d++) {
      double2* T = Tg + (size_t)((b*3 + d)*21)*256;
      double c1 = cos(u[d]);
      double s1 = sin(u[d]);
      T[10*256 + a] = make_double2(1.0, 0.0);
      T[11*256 + a] = make_double2(c1,  s1);
      T[ 9*256 + a] = make_double2(c1, -s1);
      double cp = c1, sp = s1;
      for (int n = 2; n <= 10; n++) {
        double cn = cp*c1 - sp*s1;
        double sn = sp*c1 + cp*s1;
        cp = cn; sp = sn;
        T[(10+n)*256 + a] = make_double2(cp,  sp);
        T[(10-n)*256 + a] = make_double2(cp, -sp);
      }
    }
  }
  const double ksqmax = (TWO_PI_D/1.5)*(TWO_PI_D/1.5);
  for (int m = tid; m < TOTALK; m += 256) {
    int n1 = m/441 - 10;
    int n2 = (m/21)%21 - 10;
    int n3 = m%21 - 10;
    bool half = (n1 > 0) || (n1 == 0 && (n2 > 0 || (n2 == 0 && n3 > 0)));
    if (!half) continue;
    double d1 = n1, d2 = n2, d3 = n3;
    double kx = TWO_PI_D*(ivs[0]*d1 + ivs[1]*d2 + ivs[2]*d3);
    double ky = TWO_PI_D*(ivs[3]*d1 + ivs[4]*d2 + ivs[5]*d3);
    double kz = TWO_PI_D*(ivs[6]*d1 + ivs[7]*d2 + ivs[8]*d3);
    double k2 = kx*kx + ky*ky + kz*kz;
    if (k2 > 1e-10 && k2 < ksqmax) {
      double w = 2.0 * prefs * exp(-0.5*k2) / k2;
      int slot = atomicAdd(&cnt, 1);
      klist[b*KCAP + slot] = make_int4(n1, n2, n3, 0);
      kw[b*KCAP + slot] = w;
    }
  }
  // aug borders (plane0 real values, planes 1,2 zeros)
  {
    const float* chi = nullptr; const int* znum = nullptr;
    classify2(c0, c1, c2, chi, znum);
    double* P0b = P0g + (size_t)b*NP1*WROW;
    double* P1b = P1g + (size_t)b*NP1*WROW;
    double* P2b = P2g + (size_t)b*NP1*WROW;
    for (int i = tid; i < NATOM; i += 256) {
      P0b[(size_t)NATOM*WROW + i] = 1.0;
      P0b[(size_t)i*WROW + NATOM] = 1.0;
      P0b[(size_t)i*WROW + 257]   = -(double)chi[b*NATOM + i];
      if (nplanes > 1) {
        P1b[(size_t)NATOM*WROW + i] = 0.0;
        P1b[(size_t)i*WROW + NATOM] = 0.0;
        P1b[(size_t)i*WROW + 257]   = 0.0;
      }
      if (nplanes > 2) {
        P2b[(size_t)NATOM*WROW + i] = 0.0;
        P2b[(size_t)i*WROW + NATOM] = 0.0;
        P2b[(size_t)i*WROW + 257]   = 0.0;
      }
    }
    if (tid == 0) {
      P0b[(size_t)NATOM*WROW + NATOM] = 0.0;
      P0b[(size_t)NATOM*WROW + 257]   = (double)syschg[b]*sqrt(90.0474);
      if (nplanes > 1) {
        P1b[(size_t)NATOM*WROW + NATOM] = 0.0;
        P1b[(size_t)NATOM*WROW + 257]   = 0.0;
      }
      if (nplanes > 2) {
        P2b[(size_t)NATOM*WROW + NATOM] = 0.0;
        P2b[(size_t)NATOM*WROW + 257]   = 0.0;
      }
    }
  }
  __syncthreads();
  if (tid == 0) kcount[b] = cnt;
}

// ---------------- fp64 tile GEMM into aug-geometry plane ----------------
__device__ void gemm_tile(int b, int ti, int tj, int tid,
                          const double2* __restrict__ Tg,
                          const int4* __restrict__ klist,
                          const double* __restrict__ kw, int ks, int ke,
                          double* __restrict__ Ab, bool mirror, GemmSh& S)
{
  const int tx = tid & 15, ty = tid >> 4;
  const int ro = ty << 2, co = tx << 2;
  double acc[16];
#pragma unroll
  for (int i = 0; i < 16; i++) acc[i] = 0.0;

  for (int k0 = ks; k0 < ke; k0 += KC) {
    if (tid < KC) {
      int kk = k0 + tid;
      if (kk < ke) { S.kn[tid] = klist[b*KCAP + kk]; S.kw[tid] = kw[b*KCAP + kk]; }
      else         { S.kn[tid] = make_int4(0,0,0,0); S.kw[tid] = 0.0; }
    }
    __syncthreads();
#pragma unroll
    for (int p = 0; p < 8; p++) {
      int idx = p*256 + tid;
      int a    = idx & 63;
      int kk   = (idx >> 6) & (KC-1);
      int side = idx >> 10;
      int atom = ((side == 0) ? ti : tj) + a;
      int4 nn = S.kn[kk];
      double2 t1 = Tg[(size_t)((b*3+0)*21 + (nn.x+10))*256 + atom];
      double2 t2 = Tg[(size_t)((b*3+1)*21 + (nn.y+10))*256 + atom];
      double2 t3 = Tg[(size_t)((b*3+2)*21 + (nn.z+10))*256 + atom];
      double ex = t1.x*t2.x - t1.y*t2.y;
      double ey = t1.x*t2.y + t1.y*t2.x;
      double cx = ex*t3.x - ey*t3.y;
      double cy = ex*t3.y + ey*t3.x;
      if (side == 0) { double w = S.kw[kk]; S.cI[kk][a] = w*cx; S.sI[kk][a] = w*cy; }
      else           { S.cJ[kk][a] = cx; S.sJ[kk][a] = cy; }
    }
    __syncthreads();
#pragma unroll
    for (int kk = 0; kk < KC; kk++) {
      double ci[4], si[4], cj[4], sj[4];
#pragma unroll
      for (int r = 0; r < 2; r++) {
        double2 v0 = *(const double2*)&S.cI[kk][ro + 2*r];
        ci[2*r] = v0.x; ci[2*r+1] = v0.y;
        double2 v1 = *(const double2*)&S.sI[kk][ro + 2*r];
        si[2*r] = v1.x; si[2*r+1] = v1.y;
        double2 v2 = *(const double2*)&S.cJ[kk][co + 2*r];
        cj[2*r] = v2.x; cj[2*r+1] = v2.y;
        double2 v3 = *(const double2*)&S.sJ[kk][co + 2*r];
        sj[2*r] = v3.x; sj[2*r+1] = v3.y;
      }
#pragma unroll
      for (int r = 0; r < 4; r++)
#pragma unroll
        for (int c = 0; c < 4; c++)
          acc[r*4+c] += ci[r]*cj[c] + si[r]*sj[c];
    }
    __syncthreads();
  }
#pragma unroll
  for (int r = 0; r < 4; r++) {
#pragma unroll
    for (int c = 0; c < 4; c++) {
      int gr = ti + ro + r, gc = tj + co + c;
      double v = acc[r*4+c];
      Ab[(size_t)gr*WROW + gc] = v;
      if (mirror && ti != tj) Ab[(size_t)gc*WROW + gr] = v;
    }
  }
  __syncthreads();
}

__device__ __forceinline__ double* plane_sel(double* P0, double* P1, double* P2, int s) {
  return (s == 0) ? P0 : ((s == 1) ? P1 : P2);
}

// ---------------- K2 (grid 80*nplanes): tiles x batches x k-splits ----------------
__global__ __launch_bounds__(256) void build_A_gemm(
    const double2* __restrict__ Tg, const int4* __restrict__ klist,
    const double* __restrict__ kw, const int* __restrict__ kcount,
    double* __restrict__ P0g, double* __restrict__ P1g, double* __restrict__ P2g,
    int nplanes)
{
  __shared__ GemmSh S;
  const int u = blockIdx.x;
  const int s = u / 80;
  const int r = u - s*80;
  const int b = r / 10;
  const int t = r - b*10;
  const int cnt = kcount[b];
  const int ks = (int)((long long)cnt * s / nplanes);
  const int ke = (int)((long long)cnt * (s+1) / nplanes);
  double* Ab = plane_sel(P0g, P1g, P2g, s) + (size_t)b*NP1*WROW;
  gemm_tile(b, TI10[t]*64, TJ10[t]*64, threadIdx.x, Tg, klist, kw, ks, ke, Ab, true, S);
}

// ---------------- K3 (grid 8): exact-poison tile check + rebuild ----------------
__global__ __launch_bounds__(256) void finish_A(
    const double2* __restrict__ Tg, const int4* __restrict__ klist,
    const double* __restrict__ kw, const int* __restrict__ kcount,
    double* __restrict__ P0g, double* __restrict__ P1g, double* __restrict__ P2g,
    int nplanes)
{
  __shared__ GemmSh S;
  const int b = blockIdx.x;
  const int tid = threadIdx.x;
  const int cnt = kcount[b];
  for (int s = 0; s < nplanes; s++) {
    const int ks = (int)((long long)cnt * s / nplanes);
    const int ke = (int)((long long)cnt * (s+1) / nplanes);
    double* Ab = plane_sel(P0g, P1g, P2g, s) + (size_t)b*NP1*WROW;
    for (int t = 0; t < 16; t++) {
      const int ti = (t >> 2)*64, tj = (t & 3)*64;
      int bad = 0;
#pragma unroll
      for (int k = 0; k < 8; k++) {
        int p = (tid << 4) + k;
        int r = p >> 6, c = p & 63;
        double v = Ab[(size_t)(ti+r)*WROW + tj + c];
        if (__double_as_longlong(v) == (long long)0xAAAAAAAAAAAAAAAAULL) bad = 1;
      }
      if (__syncthreads_or(bad))
        gemm_tile(b, ti, tj, tid, Tg, klist, kw, ks, ke, Ab, false, S);
      __syncthreads();
    }
  }
}

// ---------------- K4 (grid 8, block 1024): no-pivot blocked LU ----------------
// K = A + diag(J^2) - sub is PD (QEq hardness matrix); bordered system's leading
// minors are K's -> LU without pivoting is stable. 5 barriers per panel.
__global__ __launch_bounds__(BD) void solve_all(
    double* __restrict__ P0g, const double* __restrict__ P1g, const double* __restrict__ P2g,
    int nplanes,
    const void* __restrict__ c0, const void* __restrict__ c1, const void* __restrict__ c2,
    const float* __restrict__ Jraw, const float* __restrict__ syschg,
    float* __restrict__ out)
{
  const int b = blockIdx.x;
  const int tid = threadIdx.x;
  double* Pb = P0g + (size_t)b*NP1*WROW;
  const double* Qb = P1g + (size_t)b*NP1*WROW;
  const double* Rb = P2g + (size_t)b*NP1*WROW;
  const bool two   = (nplanes > 1);
  const bool three = (nplanes > 2);

  __shared__ double pan[NP1][18];
  __shared__ double dnv[NB];
  __shared__ double Ub[NB][256];
  __shared__ double xs[NP1];
  __shared__ double red[BD];

  const float* chi = nullptr; const int* znum = nullptr;
  classify2(c0, c1, c2, chi, znum);
  const double rhsN = (double)syschg[b] * sqrt(90.0474);
  const float J0 = Jraw[0], J1 = Jraw[1], J2 = Jraw[2], J3 = Jraw[3];

  for (int p0 = 0; p0 < NP1; p0 += NB) {
    const int pw  = (NB < NP1 - p0) ? NB : (NP1 - p0);
    const int nr  = NP1 - p0;
    const int nrt = nr - pw;
    const int tc0 = p0 + pw;
    const int tc  = WROW - tc0;
    const bool first = (p0 == 0);
    // ---- 1. panel load (first panel: fused plane-sum + J-diag) ----
    for (int idx = tid; idx < nr*pw; idx += BD) {
      int r = (pw == NB) ? (idx >> 4) : (idx / pw);
      int c = (pw == NB) ? (idx & 15) : (idx - r*pw);
      double v;
      if (first) {
        size_t a = (size_t)r*WROW + c;
        v = Pb[a];
        if (two)   v += Qb[a];
        if (three) v += Rb[a];
        if (r == c) {
          int z = znum[b*NATOM + r];
          float Jr = (z == 1) ? J0 : (z == 6) ? J1 : (z == 7) ? J2 : J3;
          v += (double)Jr*(double)Jr - DIAG_SUB;
        }
      } else {
        v = Pb[(size_t)(p0+r)*WROW + p0 + c];
      }
      pan[r][c] = v;
    }
    __syncthreads();
    // ---- 2. diag 16x16 factor: 16 lanes, registers + shfl (no pivoting) ----
    if (pw == NB) {
      if (tid < NB) {
        double v[NB];
#pragma unroll
        for (int c = 0; c < NB; c++) v[c] = pan[tid][c];
#pragma unroll
        for (int c = 0; c < NB; c++) {
          double uc[NB];
#pragma unroll
          for (int cc = 0; cc < NB; cc++) uc[cc] = __shfl(v[cc], c);
          double dinv = 1.0 / uc[c];
          if (tid == c) dnv[c] = dinv;
          if (tid > c) {
            double f = v[c] * dinv;
            v[c] = f;
#pragma unroll
            for (int cc = 0; cc < NB; cc++) if (cc > c) v[cc] -= f * uc[cc];
          }
        }
#pragma unroll
        for (int c = 0; c < NB; c++) pan[tid][c] = v[c];
      }
    } else {
      if (tid == 0) dnv[0] = 1.0 / pan[0][0];   // last panel: pw==1
    }
    __syncthreads();
    // ---- 3. L21 row-TRSM (barrier-free, thread-per-row) + diag write-back ----
    if (pw == NB) {
      if (tid < nrt) {
        const int r = NB + tid;
        double w[NB];
#pragma unroll
        for (int c = 0; c < NB; c++) w[c] = pan[r][c];
#pragma unroll
        for (int c = 0; c < NB; c++) {
          double s = w[c];
#pragma unroll
          for (int c2 = 0; c2 < NB; c2++) if (c2 < c) s -= w[c2] * pan[c2][c];
          w[c] = s * dnv[c];
        }
#pragma unroll
        for (int c = 0; c < NB; c++) pan[r][c] = w[c];
      } else if (tid >= 768 && tid < 768 + NB*NB) {
        int t2 = tid - 768;
        int r = t2 >> 4, c = t2 & 15;
        Pb[(size_t)(p0+r)*WROW + p0 + c] = pan[r][c];   // U11 (and L11) for backsolve
      }
    } else {
      if (tid == 0) Pb[(size_t)p0*WROW + p0] = pan[0][0];
    }
    __syncthreads();
    // ---- 4. U12 TRSM (thread-per-column) ----
    if (pw == NB) {
      if (tid < tc) {
        const int j = tc0 + tid;
        double v[NB];
#pragma unroll
        for (int c = 0; c < NB; c++) {
          size_t a = (size_t)(p0+c)*WROW + j;
          double t = Pb[a];
          if (first) {
            if (two)   t += Qb[a];
            if (three) t += Rb[a];
          }
          v[c] = t;
        }
#pragma unroll
        for (int c = 0; c < NB; c++)
#pragma unroll
          for (int r = c+1; r < NB; r++) v[r] -= pan[r][c]*v[c];
#pragma unroll
        for (int c = 0; c < NB; c++) {
          Pb[(size_t)(p0+c)*WROW + j] = v[c];
          Ub[c][tid] = v[c];
        }
      }
      __syncthreads();
      // ---- 5. trailing rank-16 update, double2 col-pairs x 8 row-groups ----
      {
        const int jp = tid & 127;
        const int rgroup = tid >> 7;
        if (2*jp < tc) {
          const int j0 = 2*jp, j1 = 2*jp + 1;
          double va[NB], vb[NB];
#pragma unroll
          for (int c = 0; c < NB; c++) { va[c] = Ub[c][j0]; vb[c] = Ub[c][j1]; }
          for (int rr = rgroup; rr < nrt; rr += 8) {
            const int row = tc0 + rr;
            const size_t addr = (size_t)row*WROW + tc0 + j0;
            double2 a = *(double2*)&Pb[addr];
            if (first) {
              if (two)   { double2 q2 = *(const double2*)&Qb[addr]; a.x += q2.x; a.y += q2.y; }
              if (three) { double2 r2 = *(const double2*)&Rb[addr]; a.x += r2.x; a.y += r2.y; }
              if (row < NATOM && (rr == j0 || rr == j1)) {
                int z = znum[b*NATOM + row];
                float Jr = (z == 1) ? J0 : (z == 6) ? J1 : (z == 7) ? J2 : J3;
                double dv = (double)Jr*(double)Jr - DIAG_SUB;
                if (rr == j0) a.x += dv; else a.y += dv;
              }
            }
#pragma unroll
            for (int m = 0; m < 8; m++) {
              double2 p2 = *(const double2*)&pan[NB+rr][2*m];
              a.x -= p2.x * va[2*m] + p2.y * va[2*m+1];
              a.y -= p2.x * vb[2*m] + p2.y * vb[2*m+1];
            }
            *(double2*)&Pb[addr] = a;
          }
        }
      }
    }
    // last panel (pw==1): L11 = 1 -> rhs col unchanged; no trailing rows
    __syncthreads();
  }

  // ---- blocked backsolve ----
  for (int r = tid; r < NP1; r += BD) xs[r] = Pb[(size_t)r*WROW + 257];
  __syncthreads();
  for (int pb0 = 256; pb0 >= 0; pb0 -= NB) {
    const int w = (pb0 == 256) ? 1 : NB;
    if (tid < w*w) {
      int i = (w == NB) ? (tid >> 4) : 0;
      int c = (w == NB) ? (tid & 15) : 0;
      pan[i][c] = Pb[(size_t)(pb0+i)*WROW + pb0 + c];
    }
    __syncthreads();
    if (tid == 0) {
      for (int i = w-1; i >= 0; i--) {
        double s = xs[pb0+i];
        for (int c = i+1; c < w; c++) s -= pan[i][c]*xs[pb0+c];
        xs[pb0+i] = s / pan[i][i];
      }
    }
    __syncthreads();
    if (tid < pb0) {
      const double* rowp = &Pb[(size_t)tid*WROW + pb0];
      double s = 0.0;
      for (int c = 0; c < w; c++) s += rowp[c]*xs[pb0+c];
      xs[tid] -= s;
    }
    __syncthreads();
  }

  // ---- outputs: q + residual-identity energy ----
  for (int i = tid; i < NATOM; i += BD) out[b*NATOM + i] = (float)xs[i];
  const double lam = xs[NATOM];
  double contrib = 0.0;
  if (tid < NATOM) {
    double q  = xs[tid];
    double ch = (double)chi[b*NATOM + tid];
    int z = znum[b*NATOM + tid];
    float Jr = (z == 1) ? J0 : (z == 6) ? J1 : (z == 7) ? J2 : J3;
    contrib = q*ch + (double)Jr*(double)Jr*q*q;
  }
  __syncthreads();
  red[tid] = contrib;
  __syncthreads();
  for (int st = BD/2; st > 0; st >>= 1) {
    if (tid < st) red[tid] += red[tid + st];
    __syncthreads();
  }
  if (tid == 0)
    out[NBATCH*NATOM + b] = (float)(-0.5*(red[0] + lam*rhsN));
}

// ---------------- host launch ----------------
extern "C" void kernel_launch(void* const* d_in, const int* in_sizes, int n_in,
                              void* d_out, int out_size, void* d_ws, size_t ws_size,
                              hipStream_t stream)
{
  int iPos=-1, iCell=-1, iJ=-1, iQ=-1, cand[3]={-1,-1,-1}, nc=0;
  for (int i = 0; i < n_in; i++) {
    int s = in_sizes[i];
    if      (s == 6144) iPos  = i;
    else if (s == 72)   iCell = i;
    else if (s == 4)    iJ    = i;
    else if (s == 8)    iQ    = i;
    else if (s == 2048 && nc < 3) cand[nc++] = i;
  }
  if (!(iPos>=0 && iCell>=0 && iJ>=0 && iQ>=0 && nc>=2)) {
    iPos=iCell=iJ=iQ=-1; nc=0; cand[0]=cand[1]=cand[2]=-1;
    for (int i = 0; i < n_in; i++) {
      int s = in_sizes[i];
      if      (s == 24576) iPos  = i;
      else if (s == 288)   iCell = i;
      else if (s == 16)    iJ    = i;
      else if (s == 32)    iQ    = i;
      else if (s == 8192 && nc < 3) cand[nc++] = i;
    }
  }
  if (!(iPos>=0 && iCell>=0 && iJ>=0 && iQ>=0 && nc>=2)) {
    iPos=0; iCell=1; iJ=3; iQ=4; cand[0]=2; cand[1]=5; cand[2]=6; nc=3;
  }
  if (nc == 2) cand[2] = cand[1];

  const float* pos  = (const float*)d_in[iPos];
  const float* cell = (const float*)d_in[iCell];
  const float* Jraw = (const float*)d_in[iJ];
  const float* sysq = (const float*)d_in[iQ];
  const void*  c0   = d_in[cand[0]];
  const void*  c1   = d_in[cand[1]];
  const void*  c2   = d_in[cand[2]];
  float* out = (float*)d_out;

  // ws: [plane0][plane1][plane2][Tg][klist][kw][kcount]
  const size_t planeB = (size_t)NBATCH*NP1*WROW*sizeof(double);  // 4,243,584
  const size_t tgB = 2064384, klB = 327680, kwB = 163840;
  const size_t trigAll = tgB + klB + kwB + 64;
  int nplanes = (ws_size >= 3*planeB + trigAll) ? 3 :
                ((ws_size >= 2*planeB + trigAll) ? 2 : 1);

  char* ws = (char*)d_ws;
  double*  P0g = (double*)ws;
  double*  P1g = (nplanes > 1) ? (double*)(ws + planeB)   : P0g;
  double*  P2g = (nplanes > 2) ? (double*)(ws + 2*planeB) : P1g;
  char* trigBase = ws + (size_t)nplanes*planeB;
  double2* Tg     = (double2*)trigBase;
  int4*    klist  = (int4*)  (trigBase + tgB);
  double*  kwa    = (double*)(trigBase + tgB + klB);
  int*     kcount = (int*)   (trigBase + tgB + klB + kwB);

  hipLaunchKernelGGL(prep,         dim3(NBATCH),      dim3(256), 0, stream,
                     pos, cell, Tg, klist, kwa, kcount, c0, c1, c2, sysq,
                     P0g, P1g, P2g, nplanes);
  hipLaunchKernelGGL(build_A_gemm, dim3(80*nplanes),  dim3(256), 0, stream,
                     Tg, klist, kwa, kcount, P0g, P1g, P2g, nplanes);
  hipLaunchKernelGGL(finish_A,     dim3(NBATCH),      dim3(256), 0, stream,
                     Tg, klist, kwa, kcount, P0g, P1g, P2g, nplanes);
  hipLaunchKernelGGL(solve_all,    dim3(NBATCH),      dim3(BD),  0, stream,
                     P0g, P1g, P2g, nplanes, c0, c1, c2, Jraw, sysq, out);
}